// Round 7
// baseline (270.621 us; speedup 1.0000x reference)
//
#include <hip/hip_runtime.h>
#include <stdint.h>

#define GM 4096
#define GN 4096
#define GK 4096
#define QW (GN/8)   /* 512 packed words per k-row */

typedef __attribute__((ext_vector_type(4))) int   i32x4;
typedef __attribute__((ext_vector_type(8))) short bf16x8;
typedef __attribute__((ext_vector_type(4))) float f32x4;

#define AS1 __attribute__((address_space(1)))
#define AS3 __attribute__((address_space(3)))

static __device__ __forceinline__ void glds16(const void* g, void* l) {
  __builtin_amdgcn_global_load_lds((const AS1 uint32_t*)g, (AS3 uint32_t*)l, 16, 0, 0);
}

static __device__ __forceinline__ uint32_t bf16pack_rn(float hi, float lo) {
  uint32_t h = __float_as_uint(hi) + 0x8000u;
  uint32_t l = __float_as_uint(lo) + 0x8000u;
  return __builtin_amdgcn_perm(h, l, 0x07060302u);
}

static __device__ __forceinline__ uint32_t pack4i8(int b0, int b1, int b2, int b3) {
  return ((uint32_t)b0 & 255u) | (((uint32_t)b1 & 255u) << 8) |
         (((uint32_t)b2 & 255u) << 16) | (((uint32_t)b3 & 255u) << 24);
}

// ---------- Fused prep kernel: a_quant ∥ w_quant(local winv) ∥ w_scale -------
// Identical to round-6 (verified passing): Ai row-major i8; Bf FRAGMENT-MAJOR
// Bf[n16][kc][lane16][16B] with lane16 = (n&15) + 16*((k>>4)&3), so one MFMA
// B-fragment (16 cols x 64 k) is a contiguous, wave-coalesced 1 KB chunk.
__global__ void __launch_bounds__(256) prep(const float* __restrict__ A,
                                            const float* __restrict__ S,
                                            const uint32_t* __restrict__ Q,
                                            int8_t* __restrict__ Ai,
                                            float* __restrict__ ascale,
                                            int8_t* __restrict__ Bf,
                                            float* __restrict__ wscale) {
  __shared__ uint32_t T32[128 * 32];             // 16 KB (w_quant role)
  __shared__ float4   red[8][32];                // 4 KB  (winv reduce)
  __shared__ float    winv_l[128];

  const int b   = blockIdx.x;
  const int tid = threadIdx.x;

  if (b < 1024) {
    // ---- a_quant role: A fp32 -> i8 per-row quant, one wave per row ----
    const int lane = tid & 63;
    const int row  = b * 4 + (tid >> 6);
    const float* src = A + (size_t)row * GK;
    float4 v[16];
    float m = 0.f;
    #pragma unroll
    for (int i = 0; i < 16; ++i) {
      v[i] = *(const float4*)(src + i * 256 + lane * 4);
      m = fmaxf(m, fmaxf(fmaxf(fabsf(v[i].x), fabsf(v[i].y)),
                         fmaxf(fabsf(v[i].z), fabsf(v[i].w))));
    }
    #pragma unroll
    for (int off = 32; off >= 1; off >>= 1)
      m = fmaxf(m, __shfl_xor(m, off, 64));
    const float rmax = fmaxf(m, 1e-20f);
    const float inv  = 127.0f / rmax;
    #pragma unroll
    for (int i = 0; i < 16; ++i) {
      uint32_t bb = pack4i8((int)__builtin_rintf(v[i].x * inv),
                            (int)__builtin_rintf(v[i].y * inv),
                            (int)__builtin_rintf(v[i].z * inv),
                            (int)__builtin_rintf(v[i].w * inv));
      *(uint32_t*)(Ai + (size_t)row * GK + i * 256 + lane * 4) = bb;
    }
    if (lane == 0) ascale[row] = rmax * (1.0f / 127.0f);
  } else if (b < 2048) {
    // ---- w_quant role: int4 -> i8, fragment-major Bf output ----
    const int wb = b - 1024;
    const int n0 = (wb & 31) * 128;
    const int k0 = (wb >> 5) * 128;
    const int g  = wb >> 5;
    const int w  = tid & 15;
    const int kb = tid >> 4;

    // local winv: max over 32 groups for this block's 128 columns
    {
      const int c4 = tid & 31;          // col quad (4 cols)
      const int g8 = tid >> 5;          // 0..7, each covers 4 groups
      float4 m4 = make_float4(0.f, 0.f, 0.f, 0.f);
      #pragma unroll
      for (int gg = 0; gg < 4; ++gg) {
        float4 sv = *(const float4*)(S + (size_t)(g8 * 4 + gg) * GN + n0 + c4 * 4);
        m4.x = fmaxf(m4.x, sv.x); m4.y = fmaxf(m4.y, sv.y);
        m4.z = fmaxf(m4.z, sv.z); m4.w = fmaxf(m4.w, sv.w);
      }
      red[g8][c4] = m4;
      __syncthreads();
      if (g8 == 0) {
        float4 m = red[0][c4];
        #pragma unroll
        for (int rr = 1; rr < 8; ++rr) {
          float4 o = red[rr][c4];
          m.x = fmaxf(m.x, o.x); m.y = fmaxf(m.y, o.y);
          m.z = fmaxf(m.z, o.z); m.w = fmaxf(m.w, o.w);
        }
        winv_l[c4 * 4 + 0] = 127.0f / (8.0f * m.x);
        winv_l[c4 * 4 + 1] = 127.0f / (8.0f * m.y);
        winv_l[c4 * 4 + 2] = 127.0f / (8.0f * m.z);
        winv_l[c4 * 4 + 3] = 127.0f / (8.0f * m.w);
      }
      __syncthreads();
    }

    float r[8], c[8];
    {
      const float* sp = S + (size_t)g * GN + n0 + w * 8;
      float4 sa = *(const float4*)sp, sb = *(const float4*)(sp + 4);
      float4 ia = *(const float4*)&winv_l[w * 8];
      float4 ib = *(const float4*)&winv_l[w * 8 + 4];
      const float sv[8] = {sa.x, sa.y, sa.z, sa.w, sb.x, sb.y, sb.z, sb.w};
      const float iv[8] = {ia.x, ia.y, ia.z, ia.w, ib.x, ib.y, ib.z, ib.w};
      #pragma unroll
      for (int j = 0; j < 8; ++j) { r[j] = sv[j] * iv[j]; c[j] = -8.0f * r[j]; }
    }

    const int swz = 4 * (w & 7);
    #pragma unroll
    for (int c2 = 0; c2 < 2; ++c2) {
      uint32_t q[4];
      #pragma unroll
      for (int i = 0; i < 4; ++i)
        q[i] = Q[(size_t)(k0 + c2 * 64 + kb * 4 + i) * QW + (n0 >> 3) + w];
      const int kword = c2 * 16 + kb;
      #pragma unroll
      for (int j = 0; j < 8; ++j) {
        int bb[4];
        #pragma unroll
        for (int i = 0; i < 4; ++i) {
          float nib = (float)((q[i] >> (4 * j)) & 0xFu);
          bb[i] = (int)__builtin_rintf(fmaf(nib, r[j], c[j]));
        }
        T32[(w * 8 + j) * 32 + (kword ^ swz)] = pack4i8(bb[0], bb[1], bb[2], bb[3]);
      }
    }
    __syncthreads();
    // readout: coalesced 1KB-per-wave fragment-major stores
    {
      const int l16 = tid & 63;
      const int sub = tid >> 6;              // 0..3
      #pragma unroll
      for (int p = 0; p < 4; ++p) {
        const int d     = p * 4 + sub;       // 0..15: 8 n16-tiles x 2 kc
        const int n16l  = d >> 1;
        const int kcl   = d & 1;
        const int col_l = n16l * 16 + (l16 & 15);
        const int gr    = (kcl << 2) | ((l16 >> 4) & 3);
        uint4 v = *(const uint4*)(&T32[col_l * 32 + ((gr ^ ((col_l >> 3) & 7)) << 2)]);
        const size_t n16g = (size_t)((n0 >> 4) + n16l);
        const size_t kcg  = (size_t)((k0 >> 6) + kcl);
        *(uint4*)(Bf + (((n16g << 6) + kcg) << 10) + (l16 << 4)) = v;
      }
    }
  } else {
    // ---- w_scale role: per-column wscale = 8*max_g s / 127 (gemm epilogue) --
    const int n = (b - 2048) * 256 + tid;
    float m = 0.f;
    #pragma unroll 8
    for (int gg = 0; gg < 32; ++gg) m = fmaxf(m, S[(size_t)gg * GN + n]);
    wscale[n] = m * (8.0f / 127.0f);
  }
}

// ---------- Kernel 3: i8 GEMM, GLOBAL-DIRECT, ZERO LDS, ZERO BARRIERS -------
// Round-7: r1-r6 all plateau at 73-88us because block-wide barriers lockstep
// every wave on a SIMD into the same phase -> MFMA pipe idles in every load
// window (additive time). This kernel removes the lockstep entirely (AITER
// s02 pattern): per wave, per K64 step: {16 MFMA on reg set s; issue 8 global
// loads for step t+2 into set s}. No __syncthreads, no manual waitcnt — the
// only waits are compiler-inserted counted vmcnt on true register deps.
// Waves skew freely; one wave's load window hides under others' MFMAs (m114).
//   A-frag (row-major Ai): lane l -> Ai[(mrow + (l&15))*K + kc*64 + (l>>4)*16]
//     = 16 fully-consumed 64B lines per load (lanes {r,r+16,r+32,r+48} contig).
//   B-frag: r6's fragment-major Bf, contiguous 1KB per fragment, verified.
// Block 256 thr = 4 waves (2wm x 2wn), tile 128x128, per-wave 64x64.
// Grid 1024: xcd=bid&7 owns 4 n-cols (B slice 2MB, L2-resident); 4 consecutive
// same-XCD blocks share mi (A panel L2 reuse). Dup frag loads (2 waves) -> L1.
// i8 accumulation exact -> C bitwise identical (absmax 0.234375).
__global__ void __launch_bounds__(256) gemm_i8(const int8_t* __restrict__ Ai,
                                               const int8_t* __restrict__ Bf,
                                               const float* __restrict__ ascale,
                                               const float* __restrict__ wscale,
                                               float* __restrict__ C) {
  const int tid = threadIdx.x;
  const int bid = blockIdx.x;
  // XCD-partition swizzle: xcd owns ni in [xcd*4, xcd*4+4), mi varies slowly
  const int xcd = bid & 7;
  const int s   = bid >> 3;            // 0..127
  const int mi  = s >> 2;              // 0..31
  const int ni  = (xcd << 2) | (s & 3);// 0..31
  const int m0  = mi * 128;
  const int n0  = ni * 128;

  const int lane = tid & 63;
  const int wid  = tid >> 6;
  const int wm   = wid >> 1;           // 0..1 -> m-offset wm*64
  const int wn   = wid & 1;            // 0..1 -> n-offset wn*64
  const int col  = lane & 15;
  const int quad = lane >> 4;

  // ---- per-lane fragment bases ----
  // A: row-major; lane l covers row (l&15), k-bytes (l>>4)*16 within each k64
  const int8_t* Ap = Ai + (size_t)(m0 + wm * 64 + col) * GK + quad * 16;
  // B: fragment-major; lane maps 1:1 to Bf lane16
  const int8_t* Bp = Bf + ((size_t)((n0 >> 4) + wn * 4) << 16) + (lane << 4);

  i32x4 afr[2][4], bfr[2][4];
  i32x4 acc[4][4];
  #pragma unroll
  for (int i = 0; i < 4; ++i)
    #pragma unroll
    for (int j = 0; j < 4; ++j)
      acc[i][j] = (i32x4){0, 0, 0, 0};

#define LDA(ss, kc) do {                                                     \
    _Pragma("unroll")                                                        \
    for (int m_ = 0; m_ < 4; ++m_)                                           \
      afr[ss][m_] = *(const i32x4*)(Ap + (size_t)m_ * 16 * GK                \
                                       + (size_t)(kc) * 64);                 \
  } while (0)
#define LDB(ss, kc) do {                                                     \
    _Pragma("unroll")                                                        \
    for (int n_ = 0; n_ < 4; ++n_)                                           \
      bfr[ss][n_] = *(const i32x4*)(Bp + ((size_t)n_ << 16)                  \
                                       + ((size_t)(kc) << 10));              \
  } while (0)
#define MM(ss) do {                                                          \
    _Pragma("unroll")                                                        \
    for (int m_ = 0; m_ < 4; ++m_)                                           \
      _Pragma("unroll")                                                      \
      for (int n_ = 0; n_ < 4; ++n_)                                         \
        acc[m_][n_] = __builtin_amdgcn_mfma_i32_16x16x64_i8(                 \
            afr[ss][m_], bfr[ss][n_], acc[m_][n_], 0, 0, 0);                 \
  } while (0)

  // ---- prologue: steps 0,1 in flight ----
  LDA(0, 0); LDB(0, 0);
  LDA(1, 1); LDB(1, 1);

  // ---- main loop: 64 K-steps, x2 unroll for static set indices ----
  // MFMA(set) waits (compiler vmcnt) on its own loads; loads for t+2 reuse
  // the just-consumed set and have a full step (~1000cy) to land.
  for (int it = 0; it < 32; ++it) {
    const int k2 = (2 * it + 2) & 63;   // wraps to dead-but-valid loads at end
    const int k3 = (2 * it + 3) & 63;
    MM(0);
    LDA(0, k2); LDB(0, k2);
    MM(1);
    LDA(1, k3); LDB(1, k3);
  }

  // ---- epilogue: C/D col=lane&15, row=quad*4+reg (verified layout) ----
  #pragma unroll
  for (int mt = 0; mt < 4; ++mt) {
    const int rbase = m0 + wm * 64 + mt * 16 + quad * 4;
    float4 a4 = *(const float4*)(ascale + rbase);
    const float ar[4] = {a4.x, a4.y, a4.z, a4.w};
    #pragma unroll
    for (int nt = 0; nt < 4; ++nt) {
      const int cbase = n0 + wn * 64 + nt * 16 + col;
      const float ws = wscale[cbase];
      #pragma unroll
      for (int r = 0; r < 4; ++r)
        C[(size_t)(rbase + r) * GN + cbase]
          = (float)acc[mt][nt][r] * (ar[r] * ws);
    }
  }
#undef LDA
#undef LDB
#undef MM
}

// ---------------- Fallback: fused dequant GEMM (round-2 kernel) ----------------
#define BM 128
#define BN 128
#define BK 32

__global__ void __launch_bounds__(256) w4a32_gemm(
    const float* __restrict__ A,
    const float* __restrict__ S,
    const uint32_t* __restrict__ Q,
    float* __restrict__ C)
{
  __shared__ __align__(16) ushort As[BM*BK];
  __shared__ __align__(16) ushort Bs[BN*BK];

  const int tid  = threadIdx.x;
  const int m0   = blockIdx.y*BM;
  const int n0   = blockIdx.x*BN;
  const int wcol  = tid & 15;
  const int kpair = tid >> 4;
  const int ln   = tid & 63;
  const int wid  = tid >> 6;
  const int wm   = (wid >> 1) * 64;
  const int wn   = (wid & 1) * 64;
  const int col  = ln & 15;
  const int quad = ln >> 4;

  f32x4 acc[4][4];
  #pragma unroll
  for (int i=0;i<4;++i)
    #pragma unroll
    for (int j=0;j<4;++j)
      acc[i][j] = (f32x4){0.f,0.f,0.f,0.f};

  float sv[8], cv[8];
  float4 spf0, spf1;

  const float*    Abase = A + (size_t)m0 * GK;
  const uint32_t* Qbase = Q + (size_t)(n0>>3) + wcol;

  {
    const float* sp = S + n0 + wcol*8;
    spf0 = *(const float4*)sp;
    spf1 = *(const float4*)(sp + 4);
  }

  float4 a4[4];
  uint32_t wqa, wqb;
  #pragma unroll
  for (int i=0;i<4;++i) {
    int f = tid + i*256;
    a4[i] = *(const float4*)(Abase + (size_t)(f>>3)*GK + ((f&7)*4));
  }
  wqa = Qbase[(size_t)(2*kpair)   * QW];
  wqb = Qbase[(size_t)(2*kpair+1) * QW];

  for (int k0 = 0; k0 < GK; k0 += BK) {
    if ((k0 & 127) == 0) {
      sv[0]=spf0.x; sv[1]=spf0.y; sv[2]=spf0.z; sv[3]=spf0.w;
      sv[4]=spf1.x; sv[5]=spf1.y; sv[6]=spf1.z; sv[7]=spf1.w;
      #pragma unroll
      for (int j=0;j<8;++j) cv[j] = -8.0f * sv[j];
    }

    #pragma unroll
    for (int i=0;i<4;++i) {
      int f = tid + i*256;
      int row = f>>3, c4 = f&7;
      *(uint2*)(&As[row*BK + c4*4]) =
        make_uint2(bf16pack_rn(a4[i].y, a4[i].x), bf16pack_rn(a4[i].w, a4[i].z));
    }

    {
      const int kk = (2*kpair) ^ (8*(wcol&3));
      #pragma unroll
      for (int j=0;j<8;++j) {
        float fa = (float)((wqa >> (4*j)) & 0xFu);
        float fb = (float)((wqb >> (4*j)) & 0xFu);
        float wa = fmaf(fa, sv[j], cv[j]);
        float wb = fmaf(fb, sv[j], cv[j]);
        int n = wcol*8 + j;
        *(uint32_t*)(&Bs[n*BK + kk]) = bf16pack_rn(wb, wa);
      }
    }

    int kn = k0 + BK; if (kn >= GK) kn = 0;
    if ((kn & 127) == 0) {
      const float* sp = S + (size_t)(kn>>7)*GN + n0 + wcol*8;
      spf0 = *(const float4*)sp;
      spf1 = *(const float4*)(sp + 4);
    }
    #pragma unroll
    for (int i=0;i<4;++i) {
      int f = tid + i*256;
      a4[i] = *(const float4*)(Abase + (size_t)(f>>3)*GK + kn + ((f&7)*4));
    }
    wqa = Qbase[(size_t)(kn + 2*kpair)   * QW];
    wqb = Qbase[(size_t)(kn + 2*kpair+1) * QW];

    __syncthreads();

    bf16x8 af[4], bfr[4];
    #pragma unroll
    for (int t=0;t<4;++t) {
      af[t] = *(const bf16x8*)(&As[(wm + t*16 + col)*BK + quad*8]);
      int n = wn + t*16 + col;
      int kk = (quad*8) ^ (8*((n>>3)&3));
      bfr[t] = *(const bf16x8*)(&Bs[n*BK + kk]);
    }
    #pragma unroll
    for (int mt=0;mt<4;++mt)
      #pragma unroll
      for (int nt=0;nt<4;++nt)
        acc[mt][nt] = __builtin_amdgcn_mfma_f32_16x16x32_bf16(
                          af[mt], bfr[nt], acc[mt][nt], 0, 0, 0);

    __syncthreads();
  }

  #pragma unroll
  for (int mt=0;mt<4;++mt)
    #pragma unroll
    for (int nt=0;nt<4;++nt)
      #pragma unroll
      for (int r=0;r<4;++r)
        C[(size_t)(m0 + wm + mt*16 + quad*4 + r)*GN + n0 + wn + nt*16 + col]
          = acc[mt][nt][r];
}

extern "C" void kernel_launch(void* const* d_in, const int* in_sizes, int n_in,
                              void* d_out, int out_size, void* d_ws, size_t ws_size,
                              hipStream_t stream) {
  const float*    A = (const float*)d_in[0];
  const float*    S = (const float*)d_in[1];
  const uint32_t* Q = (const uint32_t*)d_in[2];
  float*          C = (float*)d_out;

  const size_t need = (size_t)GM * GK + (size_t)GN * GK + 3 * 4096 * 4 + 4096;
  if (ws_size >= need) {
    int8_t* Ai  = (int8_t*)d_ws;                          // [M][K] i8, 16 MB
    int8_t* Bfr = Ai + (size_t)GM * GK;                   // fragment-major B, 16 MB
    float* ascale = (float*)(Bfr + (size_t)GN * GK);      // 4096 f32
    float* wscale = ascale + 4096;
    prep<<<dim3(1024 + 1024 + 16), dim3(256), 0, stream>>>(A, S, Q, Ai, ascale, Bfr, wscale);
    gemm_i8<<<dim3(1024), dim3(256), 0, stream>>>(Ai, Bfr, ascale, wscale, C);
  } else {
    w4a32_gemm<<<dim3(GN / BN, GM / BM), dim3(256), 0, stream>>>(A, S, Q, C);
  }
}

// Round 8
// 225.233 us; speedup vs baseline: 1.2015x; 1.2015x over previous
//
#include <hip/hip_runtime.h>
#include <stdint.h>

#define GM 4096
#define GN 4096
#define GK 4096
#define QW (GN/8)   /* 512 packed words per k-row */

typedef __attribute__((ext_vector_type(4))) int   i32x4;
typedef __attribute__((ext_vector_type(8))) short bf16x8;
typedef __attribute__((ext_vector_type(4))) float f32x4;

#define AS1 __attribute__((address_space(1)))
#define AS3 __attribute__((address_space(3)))

static __device__ __forceinline__ uint32_t bf16pack_rn(float hi, float lo) {
  uint32_t h = __float_as_uint(hi) + 0x8000u;
  uint32_t l = __float_as_uint(lo) + 0x8000u;
  return __builtin_amdgcn_perm(h, l, 0x07060302u);
}

static __device__ __forceinline__ uint32_t pack4i8(int b0, int b1, int b2, int b3) {
  return ((uint32_t)b0 & 255u) | (((uint32_t)b1 & 255u) << 8) |
         (((uint32_t)b2 & 255u) << 16) | (((uint32_t)b3 & 255u) << 24);
}

// ---------- Fused prep: a_quant(frag-major Af) ∥ w_quant(frag-major Bf) ∥ w_scale
// Round-8: BOTH operands stored fragment-major [t16][kc][lane16][16B] where
// lane16 = (row&15) + 16*((k>>4)&3). One MFMA fragment (16 rows x 64 k) is a
// contiguous wave-coalesced 1KB chunk -> gemm loads are single bursts.
// a_quant store algebra (lane l, chunk i, 4 bytes at k=i*256+4l of row r):
//   byte(r,k) -> m16*65536 + (k>>6)*1024 + ((r&15)+16*((k>>4)&3))*16 + (k&15)
//   = m16*65536 + i*4096 + (l>>4)*1024 + ((r&15)+16*((l>>2)&3))*16 + 4*(l&3)
__global__ void __launch_bounds__(256) prep(const float* __restrict__ A,
                                            const float* __restrict__ S,
                                            const uint32_t* __restrict__ Q,
                                            int8_t* __restrict__ Af,
                                            float* __restrict__ ascale,
                                            int8_t* __restrict__ Bf,
                                            float* __restrict__ wscale) {
  __shared__ uint32_t T32[128 * 32];             // 16 KB (w_quant role)
  __shared__ float4   red[8][32];                // 4 KB  (winv reduce)
  __shared__ float    winv_l[128];

  const int b   = blockIdx.x;
  const int tid = threadIdx.x;

  if (b < 1024) {
    // ---- a_quant role: A fp32 -> i8 per-row quant, one wave per row ----
    const int lane = tid & 63;
    const int row  = b * 4 + (tid >> 6);
    const float* src = A + (size_t)row * GK;
    float4 v[16];
    float m = 0.f;
    #pragma unroll
    for (int i = 0; i < 16; ++i) {
      v[i] = *(const float4*)(src + i * 256 + lane * 4);
      m = fmaxf(m, fmaxf(fmaxf(fabsf(v[i].x), fabsf(v[i].y)),
                         fmaxf(fabsf(v[i].z), fabsf(v[i].w))));
    }
    #pragma unroll
    for (int off = 32; off >= 1; off >>= 1)
      m = fmaxf(m, __shfl_xor(m, off, 64));
    const float rmax = fmaxf(m, 1e-20f);
    const float inv  = 127.0f / rmax;
    // fragment-major destination for this lane's 4-byte quant words
    int8_t* dst = Af + (size_t)(row >> 4) * 65536
                     + (lane >> 4) * 1024
                     + ((row & 15) + 16 * ((lane >> 2) & 3)) * 16
                     + 4 * (lane & 3);
    #pragma unroll
    for (int i = 0; i < 16; ++i) {
      uint32_t bb = pack4i8((int)__builtin_rintf(v[i].x * inv),
                            (int)__builtin_rintf(v[i].y * inv),
                            (int)__builtin_rintf(v[i].z * inv),
                            (int)__builtin_rintf(v[i].w * inv));
      *(uint32_t*)(dst + i * 4096) = bb;
    }
    if (lane == 0) ascale[row] = rmax * (1.0f / 127.0f);
  } else if (b < 2048) {
    // ---- w_quant role: int4 -> i8, fragment-major Bf output (r6-verified) ----
    const int wb = b - 1024;
    const int n0 = (wb & 31) * 128;
    const int k0 = (wb >> 5) * 128;
    const int g  = wb >> 5;
    const int w  = tid & 15;
    const int kb = tid >> 4;

    // local winv: max over 32 groups for this block's 128 columns
    {
      const int c4 = tid & 31;          // col quad (4 cols)
      const int g8 = tid >> 5;          // 0..7, each covers 4 groups
      float4 m4 = make_float4(0.f, 0.f, 0.f, 0.f);
      #pragma unroll
      for (int gg = 0; gg < 4; ++gg) {
        float4 sv = *(const float4*)(S + (size_t)(g8 * 4 + gg) * GN + n0 + c4 * 4);
        m4.x = fmaxf(m4.x, sv.x); m4.y = fmaxf(m4.y, sv.y);
        m4.z = fmaxf(m4.z, sv.z); m4.w = fmaxf(m4.w, sv.w);
      }
      red[g8][c4] = m4;
      __syncthreads();
      if (g8 == 0) {
        float4 m = red[0][c4];
        #pragma unroll
        for (int rr = 1; rr < 8; ++rr) {
          float4 o = red[rr][c4];
          m.x = fmaxf(m.x, o.x); m.y = fmaxf(m.y, o.y);
          m.z = fmaxf(m.z, o.z); m.w = fmaxf(m.w, o.w);
        }
        winv_l[c4 * 4 + 0] = 127.0f / (8.0f * m.x);
        winv_l[c4 * 4 + 1] = 127.0f / (8.0f * m.y);
        winv_l[c4 * 4 + 2] = 127.0f / (8.0f * m.z);
        winv_l[c4 * 4 + 3] = 127.0f / (8.0f * m.w);
      }
      __syncthreads();
    }

    float r[8], c[8];
    {
      const float* sp = S + (size_t)g * GN + n0 + w * 8;
      float4 sa = *(const float4*)sp, sb = *(const float4*)(sp + 4);
      float4 ia = *(const float4*)&winv_l[w * 8];
      float4 ib = *(const float4*)&winv_l[w * 8 + 4];
      const float sv[8] = {sa.x, sa.y, sa.z, sa.w, sb.x, sb.y, sb.z, sb.w};
      const float iv[8] = {ia.x, ia.y, ia.z, ia.w, ib.x, ib.y, ib.z, ib.w};
      #pragma unroll
      for (int j = 0; j < 8; ++j) { r[j] = sv[j] * iv[j]; c[j] = -8.0f * r[j]; }
    }

    const int swz = 4 * (w & 7);
    #pragma unroll
    for (int c2 = 0; c2 < 2; ++c2) {
      uint32_t q[4];
      #pragma unroll
      for (int i = 0; i < 4; ++i)
        q[i] = Q[(size_t)(k0 + c2 * 64 + kb * 4 + i) * QW + (n0 >> 3) + w];
      const int kword = c2 * 16 + kb;
      #pragma unroll
      for (int j = 0; j < 8; ++j) {
        int bb[4];
        #pragma unroll
        for (int i = 0; i < 4; ++i) {
          float nib = (float)((q[i] >> (4 * j)) & 0xFu);
          bb[i] = (int)__builtin_rintf(fmaf(nib, r[j], c[j]));
        }
        T32[(w * 8 + j) * 32 + (kword ^ swz)] = pack4i8(bb[0], bb[1], bb[2], bb[3]);
      }
    }
    __syncthreads();
    // readout: coalesced 1KB-per-wave fragment-major stores
    {
      const int l16 = tid & 63;
      const int sub = tid >> 6;              // 0..3
      #pragma unroll
      for (int p = 0; p < 4; ++p) {
        const int d     = p * 4 + sub;       // 0..15: 8 n16-tiles x 2 kc
        const int n16l  = d >> 1;
        const int kcl   = d & 1;
        const int col_l = n16l * 16 + (l16 & 15);
        const int gr    = (kcl << 2) | ((l16 >> 4) & 3);
        uint4 v = *(const uint4*)(&T32[col_l * 32 + ((gr ^ ((col_l >> 3) & 7)) << 2)]);
        const size_t n16g = (size_t)((n0 >> 4) + n16l);
        const size_t kcg  = (size_t)((k0 >> 6) + kcl);
        *(uint4*)(Bf + (((n16g << 6) + kcg) << 10) + (l16 << 4)) = v;
      }
    }
  } else {
    // ---- w_scale role: per-column wscale = 8*max_g s / 127 (gemm epilogue) --
    const int n = (b - 2048) * 256 + tid;
    float m = 0.f;
    #pragma unroll 8
    for (int gg = 0; gg < 32; ++gg) m = fmaxf(m, S[(size_t)gg * GN + n]);
    wscale[n] = m * (8.0f / 127.0f);
  }
}

// ---------- Kernel 3: i8 GEMM, GLOBAL-DIRECT, frag-major A+B, depth-3 -------
// Round-8 = round-7 with its three measured defects fixed:
//  (1) A now fragment-major (Af): every load (A and B) is ONE contiguous
//      wave-coalesced 1KB burst (r7's A was 16-way 64B-segment scatter).
//  (2) register pipeline depth 3 (afr/bfr[3]): ~2 full MFMA-steps (~1300cy)
//      of latency cover (r7 depth 2 ~650cy < L2 tail latency).
//  (3) addressing: per-lane 32-bit offsets are loop-invariant; only the
//      uniform kc*1024 advances -> scalar-side, no per-load VALU mults.
// Zero LDS, zero barriers, no manual waitcnt: waves free-run, compiler emits
// counted vmcnt on true deps (AITER-regime dataflow). 4 waves/block (2x2),
// tile 128x128, per-wave 64x64. Grid 1024, XCD-partitioned: xcd=bid&7 owns a
// 4-wide n-band (B slice 2MB L2-resident); 4 consecutive blocks share mi.
// K-tail prefetches (kc 64..65) overrun arrays by <=2KB into allocated
// workspace (Af->Bf, Bf->scale region; 52KB tail) - dead loads, never used.
// i8 accumulation exact -> C bitwise identical (absmax 0.234375).
__global__ void __launch_bounds__(256, 2) gemm_i8(const int8_t* __restrict__ Af,
                                                  const int8_t* __restrict__ Bf,
                                                  const float* __restrict__ ascale,
                                                  const float* __restrict__ wscale,
                                                  float* __restrict__ C) {
  const int tid = threadIdx.x;
  const int bid = blockIdx.x;
  const int xcd = bid & 7;
  const int s   = bid >> 3;            // 0..127
  const int mi  = s >> 2;              // 0..31
  const int ni  = (xcd << 2) | (s & 3);// 0..31
  const int m0  = mi * 128;
  const int n0  = ni * 128;

  const int lane = tid & 63;
  const int wid  = tid >> 6;
  const int wm   = wid >> 1;           // 0..1 -> m-offset wm*64
  const int wn   = wid & 1;            // 0..1 -> n-offset wn*64
  const int col  = lane & 15;
  const int quad = lane >> 4;

  // loop-invariant per-lane byte offsets (32-bit); kc*1024 is the uniform part
  const size_t aoff = ((size_t)((m0 + wm * 64) >> 4) << 16) + (lane << 4);
  const size_t boff = ((size_t)((n0 + wn * 64) >> 4) << 16) + (lane << 4);
  const int8_t* Ap = Af + aoff;
  const int8_t* Bp = Bf + boff;

  i32x4 afr[3][4], bfr[3][4];
  i32x4 acc[4][4];
  #pragma unroll
  for (int i = 0; i < 4; ++i)
    #pragma unroll
    for (int j = 0; j < 4; ++j)
      acc[i][j] = (i32x4){0, 0, 0, 0};

#define LD(ss, kc) do {                                                      \
    _Pragma("unroll")                                                        \
    for (int m_ = 0; m_ < 4; ++m_)                                           \
      afr[ss][m_] = *(const i32x4*)(Ap + ((size_t)m_ << 16)                  \
                                       + ((size_t)(kc) << 10));              \
    _Pragma("unroll")                                                        \
    for (int n_ = 0; n_ < 4; ++n_)                                           \
      bfr[ss][n_] = *(const i32x4*)(Bp + ((size_t)n_ << 16)                  \
                                       + ((size_t)(kc) << 10));              \
  } while (0)
#define MM(ss) do {                                                          \
    _Pragma("unroll")                                                        \
    for (int m_ = 0; m_ < 4; ++m_)                                           \
      _Pragma("unroll")                                                      \
      for (int n_ = 0; n_ < 4; ++n_)                                         \
        acc[m_][n_] = __builtin_amdgcn_mfma_i32_16x16x64_i8(                 \
            afr[ss][m_], bfr[ss][n_], acc[m_][n_], 0, 0, 0);                 \
  } while (0)

  // ---- prologue: 3 steps in flight ----
  LD(0, 0); LD(1, 1); LD(2, 2);

  // ---- main loop: steps 0..62 (x3 unroll, static set indices), tail 63 ----
  for (int it = 0; it < 21; ++it) {
    const int t = 3 * it;
    MM(0); LD(0, t + 3);
    MM(1); LD(1, t + 4);
    MM(2); LD(2, t + 5);   // kc up to 65: dead overrun loads, bounded, unused
  }
  MM(0);                   // step 63 (63 % 3 == 0)

  // ---- epilogue: C/D col=lane&15, row=quad*4+reg (verified layout) ----
  #pragma unroll
  for (int mt = 0; mt < 4; ++mt) {
    const int rbase = m0 + wm * 64 + mt * 16 + quad * 4;
    float4 a4 = *(const float4*)(ascale + rbase);
    const float ar[4] = {a4.x, a4.y, a4.z, a4.w};
    #pragma unroll
    for (int nt = 0; nt < 4; ++nt) {
      const int cbase = n0 + wn * 64 + nt * 16 + col;
      const float ws = wscale[cbase];
      #pragma unroll
      for (int r = 0; r < 4; ++r)
        C[(size_t)(rbase + r) * GN + cbase]
          = (float)acc[mt][nt][r] * (ar[r] * ws);
    }
  }
#undef LD
#undef MM
}

// ---------------- Fallback: fused dequant GEMM (round-2 kernel) ----------------
#define BM 128
#define BN 128
#define BK 32

__global__ void __launch_bounds__(256) w4a32_gemm(
    const float* __restrict__ A,
    const float* __restrict__ S,
    const uint32_t* __restrict__ Q,
    float* __restrict__ C)
{
  __shared__ __align__(16) ushort As[BM*BK];
  __shared__ __align__(16) ushort Bs[BN*BK];

  const int tid  = threadIdx.x;
  const int m0   = blockIdx.y*BM;
  const int n0   = blockIdx.x*BN;
  const int wcol  = tid & 15;
  const int kpair = tid >> 4;
  const int ln   = tid & 63;
  const int wid  = tid >> 6;
  const int wm   = (wid >> 1) * 64;
  const int wn   = (wid & 1) * 64;
  const int col  = ln & 15;
  const int quad = ln >> 4;

  f32x4 acc[4][4];
  #pragma unroll
  for (int i=0;i<4;++i)
    #pragma unroll
    for (int j=0;j<4;++j)
      acc[i][j] = (f32x4){0.f,0.f,0.f,0.f};

  float sv[8], cv[8];
  float4 spf0, spf1;

  const float*    Abase = A + (size_t)m0 * GK;
  const uint32_t* Qbase = Q + (size_t)(n0>>3) + wcol;

  {
    const float* sp = S + n0 + wcol*8;
    spf0 = *(const float4*)sp;
    spf1 = *(const float4*)(sp + 4);
  }

  float4 a4[4];
  uint32_t wqa, wqb;
  #pragma unroll
  for (int i=0;i<4;++i) {
    int f = tid + i*256;
    a4[i] = *(const float4*)(Abase + (size_t)(f>>3)*GK + ((f&7)*4));
  }
  wqa = Qbase[(size_t)(2*kpair)   * QW];
  wqb = Qbase[(size_t)(2*kpair+1) * QW];

  for (int k0 = 0; k0 < GK; k0 += BK) {
    if ((k0 & 127) == 0) {
      sv[0]=spf0.x; sv[1]=spf0.y; sv[2]=spf0.z; sv[3]=spf0.w;
      sv[4]=spf1.x; sv[5]=spf1.y; sv[6]=spf1.z; sv[7]=spf1.w;
      #pragma unroll
      for (int j=0;j<8;++j) cv[j] = -8.0f * sv[j];
    }

    #pragma unroll
    for (int i=0;i<4;++i) {
      int f = tid + i*256;
      int row = f>>3, c4 = f&7;
      *(uint2*)(&As[row*BK + c4*4]) =
        make_uint2(bf16pack_rn(a4[i].y, a4[i].x), bf16pack_rn(a4[i].w, a4[i].z));
    }

    {
      const int kk = (2*kpair) ^ (8*(wcol&3));
      #pragma unroll
      for (int j=0;j<8;++j) {
        float fa = (float)((wqa >> (4*j)) & 0xFu);
        float fb = (float)((wqb >> (4*j)) & 0xFu);
        float wa = fmaf(fa, sv[j], cv[j]);
        float wb = fmaf(fb, sv[j], cv[j]);
        int n = wcol*8 + j;
        *(uint32_t*)(&Bs[n*BK + kk]) = bf16pack_rn(wb, wa);
      }
    }

    int kn = k0 + BK; if (kn >= GK) kn = 0;
    if ((kn & 127) == 0) {
      const float* sp = S + (size_t)(kn>>7)*GN + n0 + wcol*8;
      spf0 = *(const float4*)sp;
      spf1 = *(const float4*)(sp + 4);
    }
    #pragma unroll
    for (int i=0;i<4;++i) {
      int f = tid + i*256;
      a4[i] = *(const float4*)(Abase + (size_t)(f>>3)*GK + kn + ((f&7)*4));
    }
    wqa = Qbase[(size_t)(kn + 2*kpair)   * QW];
    wqb = Qbase[(size_t)(kn + 2*kpair+1) * QW];

    __syncthreads();

    bf16x8 af[4], bfr[4];
    #pragma unroll
    for (int t=0;t<4;++t) {
      af[t] = *(const bf16x8*)(&As[(wm + t*16 + col)*BK + quad*8]);
      int n = wn + t*16 + col;
      int kk = (quad*8) ^ (8*((n>>3)&3));
      bfr[t] = *(const bf16x8*)(&Bs[n*BK + kk]);
    }
    #pragma unroll
    for (int mt=0;mt<4;++mt)
      #pragma unroll
      for (int nt=0;nt<4;++nt)
        acc[mt][nt] = __builtin_amdgcn_mfma_f32_16x16x32_bf16(
                          af[mt], bfr[nt], acc[mt][nt], 0, 0, 0);

    __syncthreads();
  }

  #pragma unroll
  for (int mt=0;mt<4;++mt)
    #pragma unroll
    for (int nt=0;nt<4;++nt)
      #pragma unroll
      for (int r=0;r<4;++r)
        C[(size_t)(m0 + wm + mt*16 + quad*4 + r)*GN + n0 + wn + nt*16 + col]
          = acc[mt][nt][r];
}

extern "C" void kernel_launch(void* const* d_in, const int* in_sizes, int n_in,
                              void* d_out, int out_size, void* d_ws, size_t ws_size,
                              hipStream_t stream) {
  const float*    A = (const float*)d_in[0];
  const float*    S = (const float*)d_in[1];
  const uint32_t* Q = (const uint32_t*)d_in[2];
  float*          C = (float*)d_out;

  const size_t need = (size_t)GM * GK + (size_t)GN * GK + 3 * 4096 * 4 + 4096;
  if (ws_size >= need) {
    int8_t* Afr = (int8_t*)d_ws;                          // fragment-major A, 16 MB
    int8_t* Bfr = Afr + (size_t)GM * GK;                  // fragment-major B, 16 MB
    float* ascale = (float*)(Bfr + (size_t)GN * GK);      // 4096 f32
    float* wscale = ascale + 4096;
    prep<<<dim3(1024 + 1024 + 16), dim3(256), 0, stream>>>(A, S, Q, Afr, ascale, Bfr, wscale);
    gemm_i8<<<dim3(1024), dim3(256), 0, stream>>>(Afr, Bfr, ascale, wscale, C);
  } else {
    w4a32_gemm<<<dim3(GN / BN, GM / BM), dim3(256), 0, stream>>>(A, S, Q, C);
  }
}